// Round 3
// baseline (384.607 us; speedup 1.0000x reference)
//
#include <hip/hip_runtime.h>
#include <math.h>

#define BATCH   16384
#define DMODEL  1024
#define KPACK   3072      // logical packed K  ([xh|xl|xh] . [wh|wh|wl])
#define KPHYS   2048      // physical width of packed buffers [h|l]
#define LN_EPS  1e-5f

typedef __bf16 bf16x8 __attribute__((ext_vector_type(8)));
typedef float  f32x4  __attribute__((ext_vector_type(4)));

static __device__ __forceinline__ unsigned short f2bf(float v) {
  union { float f; unsigned u; } c; c.f = v;
  unsigned r = c.u + 0x7fffu + ((c.u >> 16) & 1u);  // RNE
  return (unsigned short)(r >> 16);
}
static __device__ __forceinline__ float bf2f(unsigned short h) {
  union { unsigned u; float f; } c; c.u = ((unsigned)h) << 16;
  return c.f;
}

// async global->LDS, 16B/lane; lds dest = wave-uniform base + lane*16
static __device__ __forceinline__ void gload16(const void* g, void* l) {
  __builtin_amdgcn_global_load_lds(
      (const __attribute__((address_space(1))) void*)g,
      (__attribute__((address_space(3))) void*)l, 16, 0, 0);
}

#define S_BAR() __builtin_amdgcn_s_barrier()
#define LGKM0() do { asm volatile("s_waitcnt lgkmcnt(0)" ::: "memory"); \
                     __builtin_amdgcn_sched_barrier(0); } while (0)
#define VMC8()  do { asm volatile("s_waitcnt vmcnt(8)" ::: "memory"); \
                     __builtin_amdgcn_sched_barrier(0); } while (0)

// ---------------- weight pack: fp32 -> [hi | lo] bf16 planes ----------------
__global__ __launch_bounds__(256) void pack_kernel(
    const float* __restrict__ Wdt, const float* __restrict__ Wo,
    const float* __restrict__ Wb, const float* __restrict__ Wc,
    unsigned short* __restrict__ WdtP, unsigned short* __restrict__ WoP,
    unsigned short* __restrict__ WbcP) {
  int r = blockIdx.x;
  const float* src;
  unsigned short* dst;
  if (r < 1024)      { src = Wdt + (size_t)r * 1024;        dst = WdtP + (size_t)r * KPHYS; }
  else if (r < 2048) { src = Wo  + (size_t)(r-1024) * 1024; dst = WoP  + (size_t)(r-1024) * KPHYS; }
  else if (r < 2064) { src = Wb  + (size_t)(r-2048) * 1024; dst = WbcP + (size_t)(r-2048) * KPHYS; }
  else               { src = Wc  + (size_t)(r-2064) * 1024; dst = WbcP + (size_t)(r-2064+16) * KPHYS; }
  int t = threadIdx.x;
  float4 v = ((const float4*)src)[t];
  ushort4 hs, ls; unsigned short h;
  h = f2bf(v.x); hs.x = h; ls.x = f2bf(v.x - bf2f(h));
  h = f2bf(v.y); hs.y = h; ls.y = f2bf(v.y - bf2f(h));
  h = f2bf(v.z); hs.z = h; ls.z = f2bf(v.z - bf2f(h));
  h = f2bf(v.w); hs.w = h; ls.w = f2bf(v.w - bf2f(h));
  ((ushort4*)dst)[t] = hs;
  ((ushort4*)(dst + 1024))[t] = ls;
}

// ---------------- LayerNorm -> packed xn [hi | lo] ----------------
__global__ __launch_bounds__(256) void ln_kernel(
    const float* __restrict__ x, const float* __restrict__ gamma,
    const float* __restrict__ beta, unsigned short* __restrict__ xnp) {
  const int row = blockIdx.x;
  const int tid = threadIdx.x;
  const float4* xr = (const float4*)(x + (size_t)row * DMODEL);
  float4 v = xr[tid];
  float s = v.x + v.y + v.z + v.w;
  float q = v.x * v.x + v.y * v.y + v.z * v.z + v.w * v.w;
#pragma unroll
  for (int m = 1; m < 64; m <<= 1) {
    s += __shfl_xor(s, m, 64);
    q += __shfl_xor(q, m, 64);
  }
  __shared__ float ws[4], wq[4];
  int w = tid >> 6, l = tid & 63;
  if (l == 0) { ws[w] = s; wq[w] = q; }
  __syncthreads();
  s = ws[0] + ws[1] + ws[2] + ws[3];
  q = wq[0] + wq[1] + wq[2] + wq[3];
  float mu = s * (1.0f / DMODEL);
  float var = q * (1.0f / DMODEL) - mu * mu;
  float rs = rsqrtf(var + LN_EPS);
  float4 g = ((const float4*)gamma)[tid];
  float4 b = ((const float4*)beta)[tid];
  float xn0 = (v.x - mu) * rs * g.x + b.x;
  float xn1 = (v.y - mu) * rs * g.y + b.y;
  float xn2 = (v.z - mu) * rs * g.z + b.z;
  float xn3 = (v.w - mu) * rs * g.w + b.w;
  ushort4 hs, ls; unsigned short h;
  h = f2bf(xn0); hs.x = h; ls.x = f2bf(xn0 - bf2f(h));
  h = f2bf(xn1); hs.y = h; ls.y = f2bf(xn1 - bf2f(h));
  h = f2bf(xn2); hs.z = h; ls.z = f2bf(xn2 - bf2f(h));
  h = f2bf(xn3); hs.w = h; ls.w = f2bf(xn3 - bf2f(h));
  unsigned short* dst = xnp + (size_t)row * KPHYS;
  ((ushort4*)dst)[tid] = hs;
  ((ushort4*)(dst + 1024))[tid] = ls;
}

// ---------------- Bm/Cm -> s  (M=16384, N=32, packed K=3072) ----------------
__global__ __launch_bounds__(256) void bc_kernel(
    const unsigned short* __restrict__ XNP, const unsigned short* __restrict__ WbcP,
    const float* __restrict__ bb, const float* __restrict__ bcv, float* __restrict__ S) {
  __shared__ char smem[(64 + 32) * 128];
  char* sA = smem;
  char* sB = smem + 64 * 128;
  const int tid = threadIdx.x;
  const int l = tid & 63;
  const int w = tid >> 6;
  const int m0 = blockIdx.x * 64;
  f32x4 acc0 = {0.f, 0.f, 0.f, 0.f};
  f32x4 acc1 = {0.f, 0.f, 0.f, 0.f};
  for (int kt = 0; kt < KPACK; kt += 64) {
    int ksA = kt < 2048 ? kt : kt - 2048;   // [xh|xl|xh]
    int ksB = kt < 1024 ? kt : kt - 1024;   // [wh|wh|wl]
#pragma unroll
    for (int i = 0; i < 2; ++i) {
      int qq = i * 256 + tid;
      int row = qq >> 3, ch = qq & 7;
      gload16(XNP + (size_t)(m0 + row) * KPHYS + ksA + ((ch ^ (row & 7)) << 3),
              sA + (i * 256 + w * 64) * 16);
    }
    {
      int row = tid >> 3, ch = tid & 7;
      gload16(WbcP + (size_t)row * KPHYS + ksB + ((ch ^ (row & 7)) << 3),
              sB + (w * 64) * 16);
    }
    __syncthreads();
#pragma unroll
    for (int kk = 0; kk < 2; ++kk) {
      int cs = ((kk * 4 + (l >> 4)) ^ (l & 7)) * 16;
      bf16x8 a  = *(const bf16x8*)(sA + (w * 16 + (l & 15)) * 128 + cs);
      bf16x8 b0 = *(const bf16x8*)(sB + ((l & 15)) * 128 + cs);
      bf16x8 b1 = *(const bf16x8*)(sB + (16 + (l & 15)) * 128 + cs);
      acc0 = __builtin_amdgcn_mfma_f32_16x16x32_bf16(a, b0, acc0, 0, 0, 0);
      acc1 = __builtin_amdgcn_mfma_f32_16x16x32_bf16(a, b1, acc1, 0, 0, 0);
    }
    __syncthreads();
  }
  int c = l & 15;
#pragma unroll
  for (int j = 0; j < 4; ++j) {
    float bmv = acc0[j] + bb[c];
    float cmv = acc1[j] + bcv[c];
    float p = bmv * cmv;
    p += __shfl_xor(p, 1, 64);
    p += __shfl_xor(p, 2, 64);
    p += __shfl_xor(p, 4, 64);
    p += __shfl_xor(p, 8, 64);
    if (c == 0) S[m0 + w * 16 + (l >> 4) * 4 + j] = p;
  }
}

// ---------------- 256x256 8-phase deep-pipelined GEMM ----------------
// C[m,n] = sum_k' A[m,k']*B[n,k'] over logical K'=3072 with source remap.
// EPI 1: softplus/dt epilogue -> YP (packed h|l).  EPI 2: +bo + residual -> out.
template <int EPI>
__global__ __launch_bounds__(512, 2) void gemm8_kernel(
    const unsigned short* __restrict__ Ag,   // [16384][2048] packed h|l
    const unsigned short* __restrict__ Bg,   // [1024][2048] packed h|l
    const float* __restrict__ e0,            // EPI1: bdt   EPI2: bo
    const float* __restrict__ e1,            // EPI1: Dsk   EPI2: x (residual)
    const float* __restrict__ S,             // EPI1: s
    unsigned short* __restrict__ YP,         // EPI1 out (packed h|l)
    float* __restrict__ outf) {              // EPI2 out
  __shared__ char smem[131072];
  char* const bufA[2] = { smem, smem + 65536 };
  char* const bufB[2] = { smem + 32768, smem + 98304 };

  const int tid = threadIdx.x;
  const int l = tid & 63;
  const int w = tid >> 6;     // 8 waves
  const int wm = w >> 2;      // 0..1  (128 rows each)
  const int wn = w & 3;       // 0..3  (64 cols each)

  // bijective XCD swizzle (grid 256 = 8*32)
  const int bid = blockIdx.x;
  const int sid = (bid & 7) * 32 + (bid >> 3);
  const int m0 = (sid >> 2) * 256;
  const int n0 = (sid & 3) * 256;

  f32x4 acc[8][4];
#pragma unroll
  for (int a = 0; a < 8; ++a)
#pragma unroll
    for (int b = 0; b < 4; ++b) acc[a][b] = (f32x4){0.f, 0.f, 0.f, 0.f};

  // stage one 256x64 K-tile of A and B into buffer bufi (8 gload16/thread)
  auto STAGE = [&](int bufi, int kt) {
    const int ksA = kt < 2048 ? kt : kt - 2048;   // A logical [h|l|h]
    const int ksB = kt < 1024 ? kt : kt - 1024;   // B logical [h|h|l]
#pragma unroll
    for (int r = 0; r < 4; ++r) {
      int qq = r * 512 + tid;
      int row = qq >> 3, ch = qq & 7;
      gload16(Ag + (size_t)(m0 + row) * KPHYS + ksA + ((ch ^ (row & 7)) << 3),
              bufA[bufi] + (r * 512 + w * 64) * 16);
    }
#pragma unroll
    for (int r = 0; r < 4; ++r) {
      int qq = r * 512 + tid;
      int row = qq >> 3, ch = qq & 7;
      gload16(Bg + (size_t)(n0 + row) * KPHYS + ksB + ((ch ^ (row & 7)) << 3),
              bufB[bufi] + (r * 512 + w * 64) * 16);
    }
  };

  const int rbA = (wm * 128 + (l & 15)) * 128;
  const int rbB = (wn * 64 + (l & 15)) * 128;
  int cs[2];
  cs[0] = (((l >> 4)) ^ (l & 7)) * 16;
  cs[1] = ((4 + (l >> 4)) ^ (l & 7)) * 16;

  bf16x8 aF[4][2], bF[2][2][2];
  auto LDA = [&](int bufi, int qm) {
#pragma unroll
    for (int mi = 0; mi < 4; ++mi)
#pragma unroll
      for (int kk = 0; kk < 2; ++kk)
        aF[mi][kk] = *(const bf16x8*)(bufA[bufi] + rbA + qm * 8192 + mi * 2048 + cs[kk]);
  };
  auto LDB = [&](int bufi, int qn) {
#pragma unroll
    for (int ni = 0; ni < 2; ++ni)
#pragma unroll
      for (int kk = 0; kk < 2; ++kk)
        bF[qn][ni][kk] = *(const bf16x8*)(bufB[bufi] + rbB + qn * 4096 + ni * 2048 + cs[kk]);
  };
  auto MFMA = [&](int qm, int qn) {
    __builtin_amdgcn_s_setprio(1);
#pragma unroll
    for (int kk = 0; kk < 2; ++kk)
#pragma unroll
      for (int mi = 0; mi < 4; ++mi)
#pragma unroll
        for (int ni = 0; ni < 2; ++ni)
          acc[qm * 4 + mi][qn * 2 + ni] = __builtin_amdgcn_mfma_f32_16x16x32_bf16(
              aF[mi][kk], bF[qn][ni][kk], acc[qm * 4 + mi][qn * 2 + ni], 0, 0, 0);
    __builtin_amdgcn_s_setprio(0);
  };

  // prologue: tiles 0,1 in flight; wait tile0 (vmcnt leaves tile1's 8)
  STAGE(0, 0);
  STAGE(1, 64);
  VMC8();
  S_BAR();

  for (int it = 0; it < 24; ++it) {
    const int ktA = it * 128;
    const int kt2 = (ktA + 128 <= KPACK - 64) ? ktA + 128 : KPACK - 64;
    const int kt3 = (ktA + 192 <= KPACK - 64) ? ktA + 192 : KPACK - 64;
    // ---- tile 2it (buf0) ----
    LDA(0, 0); LDB(0, 0);                 // ph1: q(0,0)
    S_BAR(); LGKM0(); MFMA(0, 0); S_BAR();
    LDB(0, 1);                            // ph2: q(0,1)
    S_BAR(); LGKM0(); MFMA(0, 1); S_BAR();
    LDA(0, 1);                            // ph3: q(1,1)
    S_BAR(); LGKM0(); MFMA(1, 1); S_BAR();
    STAGE(0, kt2);                        // ph4: q(1,0) + stage tile+2 (buf0 free)
    S_BAR(); MFMA(1, 0); VMC8(); S_BAR(); // wait: next tile (buf1) fully landed
    // ---- tile 2it+1 (buf1) ----
    LDA(1, 0); LDB(1, 0);                 // ph5
    S_BAR(); LGKM0(); MFMA(0, 0); S_BAR();
    LDB(1, 1);                            // ph6
    S_BAR(); LGKM0(); MFMA(0, 1); S_BAR();
    LDA(1, 1);                            // ph7
    S_BAR(); LGKM0(); MFMA(1, 1); S_BAR();
    STAGE(1, kt3);                        // ph8
    S_BAR(); MFMA(1, 0); VMC8(); S_BAR();
  }

  // ---------------- epilogue ----------------
  // C/D frag: col = lane&15, row = (lane>>4)*4 + j  (verified)
  if constexpr (EPI == 1) {
#pragma unroll
    for (int a = 0; a < 8; ++a) {
      int rw = m0 + wm * 128 + (a >> 2) * 64 + (a & 3) * 16 + (l >> 4) * 4;
#pragma unroll
      for (int j = 0; j < 4; ++j) {
        int r = rw + j;
        float sv = S[r];
        size_t base = (size_t)r * KPHYS;
#pragma unroll
        for (int b = 0; b < 4; ++b) {
          int col = n0 + wn * 64 + (b >> 1) * 32 + (b & 1) * 16 + (l & 15);
          float v = acc[a][b][j] + e0[col];
          float sp = fmaxf(v, 0.f) + __logf(1.f + __expf(-fabsf(v)));
          float xnv = bf2f(Ag[base + col]) + bf2f(Ag[base + 1024 + col]);
          float y = sp * xnv * sv + xnv * e1[col];
          unsigned short h = f2bf(y);
          YP[base + col] = h;
          YP[base + 1024 + col] = f2bf(y - bf2f(h));
        }
      }
    }
  } else {
#pragma unroll
    for (int a = 0; a < 8; ++a) {
      int rw = m0 + wm * 128 + (a >> 2) * 64 + (a & 3) * 16 + (l >> 4) * 4;
#pragma unroll
      for (int j = 0; j < 4; ++j) {
        int r = rw + j;
        size_t base = (size_t)r * DMODEL;
#pragma unroll
        for (int b = 0; b < 4; ++b) {
          int col = n0 + wn * 64 + (b >> 1) * 32 + (b & 1) * 16 + (l & 15);
          outf[base + col] = acc[a][b][j] + e0[col] + e1[base + col];
        }
      }
    }
  }
}

extern "C" void kernel_launch(void* const* d_in, const int* in_sizes, int n_in,
                              void* d_out, int out_size, void* d_ws, size_t ws_size,
                              hipStream_t stream) {
  const float* x = (const float*)d_in[0];
  const float* gamma = (const float*)d_in[1];
  const float* beta = (const float*)d_in[2];
  const float* Wb = (const float*)d_in[3];
  const float* bb = (const float*)d_in[4];
  const float* Wc = (const float*)d_in[5];
  const float* bc = (const float*)d_in[6];
  const float* Wdt = (const float*)d_in[7];
  const float* bdt = (const float*)d_in[8];
  const float* Dsk = (const float*)d_in[9];
  const float* Wo = (const float*)d_in[10];
  const float* bo = (const float*)d_in[11];
  float* out = (float*)d_out;

  char* ws = (char*)d_ws;
  size_t off = 0;
  auto alloc = [&](size_t bytes) {
    char* p = ws + off;
    off = (off + bytes + 255) & ~(size_t)255;
    return p;
  };
  unsigned short* XNP  = (unsigned short*)alloc((size_t)BATCH * KPHYS * 2);
  unsigned short* YP   = (unsigned short*)alloc((size_t)BATCH * KPHYS * 2);
  unsigned short* WdtP = (unsigned short*)alloc((size_t)DMODEL * KPHYS * 2);
  unsigned short* WoP  = (unsigned short*)alloc((size_t)DMODEL * KPHYS * 2);
  unsigned short* WbcP = (unsigned short*)alloc((size_t)32 * KPHYS * 2);
  float* S = (float*)alloc((size_t)BATCH * 4);

  pack_kernel<<<2080, 256, 0, stream>>>(Wdt, Wo, Wb, Wc, WdtP, WoP, WbcP);
  ln_kernel<<<BATCH, 256, 0, stream>>>(x, gamma, beta, XNP);
  bc_kernel<<<BATCH / 64, 256, 0, stream>>>(XNP, WbcP, bb, bc, S);
  gemm8_kernel<1><<<256, 512, 0, stream>>>(XNP, WdtP, bdt, Dsk, S, YP, nullptr);
  gemm8_kernel<2><<<256, 512, 0, stream>>>(YP, WoP, bo, x, nullptr, nullptr, out);
}

// Round 10
// 369.213 us; speedup vs baseline: 1.0417x; 1.0417x over previous
//
#include <hip/hip_runtime.h>
#include <math.h>

#define BATCH   16384
#define DMODEL  1024
#define KPACK   3072      // logical packed K  ([xh|xl|xh] . [wh|wh|wl])
#define KPHYS   2048      // physical width of packed buffers [h|l]
#define LN_EPS  1e-5f

typedef __bf16 bf16x8 __attribute__((ext_vector_type(8)));
typedef float  f32x4  __attribute__((ext_vector_type(4)));

static __device__ __forceinline__ unsigned short f2bf(float v) {
  union { float f; unsigned u; } c; c.f = v;
  unsigned r = c.u + 0x7fffu + ((c.u >> 16) & 1u);  // RNE
  return (unsigned short)(r >> 16);
}
static __device__ __forceinline__ float bf2f(unsigned short h) {
  union { unsigned u; float f; } c; c.u = ((unsigned)h) << 16;
  return c.f;
}

// async global->LDS, 16B/lane; lds dest = wave-uniform base + lane*16
static __device__ __forceinline__ void gload16(const void* g, void* l) {
  __builtin_amdgcn_global_load_lds(
      (const __attribute__((address_space(1))) void*)g,
      (__attribute__((address_space(3))) void*)l, 16, 0, 0);
}

#define SCHED0() __builtin_amdgcn_sched_barrier(0)
// compiler-only memory fence: pins issue ORDER of gload16 groups (vmcnt is
// FIFO in issue order — counted waits are only exact if groups don't mix)
#define MFENCE() asm volatile("" ::: "memory")
// barrier with compiler memory fences on BOTH sides: s_barrier itself is not
// a memory fence to the optimizer.
#define SBAR_F() do { MFENCE(); __builtin_amdgcn_s_barrier(); MFENCE(); } while (0)
#define VMC8()   do { asm volatile("s_waitcnt vmcnt(8)" ::: "memory"); } while (0)
// all LDS reads retired per-wave; nothing memory-side crosses afterwards
#define LGKM0_PIN() do { asm volatile("s_waitcnt lgkmcnt(0)" ::: "memory"); \
                         __builtin_amdgcn_sched_barrier(0); } while (0)

// ---------------- weight pack: fp32 -> [hi | lo] bf16 planes ----------------
__global__ __launch_bounds__(256) void pack_kernel(
    const float* __restrict__ Wdt, const float* __restrict__ Wo,
    const float* __restrict__ Wb, const float* __restrict__ Wc,
    unsigned short* __restrict__ WdtP, unsigned short* __restrict__ WoP,
    unsigned short* __restrict__ WbcP) {
  int r = blockIdx.x;
  const float* src;
  unsigned short* dst;
  if (r < 1024)      { src = Wdt + (size_t)r * 1024;        dst = WdtP + (size_t)r * KPHYS; }
  else if (r < 2048) { src = Wo  + (size_t)(r-1024) * 1024; dst = WoP  + (size_t)(r-1024) * KPHYS; }
  else if (r < 2064) { src = Wb  + (size_t)(r-2048) * 1024; dst = WbcP + (size_t)(r-2048) * KPHYS; }
  else               { src = Wc  + (size_t)(r-2064) * 1024; dst = WbcP + (size_t)(r-2064+16) * KPHYS; }
  int t = threadIdx.x;
  float4 v = ((const float4*)src)[t];
  ushort4 hs, ls; unsigned short h;
  h = f2bf(v.x); hs.x = h; ls.x = f2bf(v.x - bf2f(h));
  h = f2bf(v.y); hs.y = h; ls.y = f2bf(v.y - bf2f(h));
  h = f2bf(v.z); hs.z = h; ls.z = f2bf(v.z - bf2f(h));
  h = f2bf(v.w); hs.w = h; ls.w = f2bf(v.w - bf2f(h));
  ((ushort4*)dst)[t] = hs;
  ((ushort4*)(dst + 1024))[t] = ls;
}

// ---------------- LayerNorm -> packed xn [hi | lo] ----------------
__global__ __launch_bounds__(256) void ln_kernel(
    const float* __restrict__ x, const float* __restrict__ gamma,
    const float* __restrict__ beta, unsigned short* __restrict__ xnp) {
  const int row = blockIdx.x;
  const int tid = threadIdx.x;
  const float4* xr = (const float4*)(x + (size_t)row * DMODEL);
  float4 v = xr[tid];
  float s = v.x + v.y + v.z + v.w;
  float q = v.x * v.x + v.y * v.y + v.z * v.z + v.w * v.w;
#pragma unroll
  for (int m = 1; m < 64; m <<= 1) {
    s += __shfl_xor(s, m, 64);
    q += __shfl_xor(q, m, 64);
  }
  __shared__ float ws[4], wq[4];
  int w = tid >> 6, l = tid & 63;
  if (l == 0) { ws[w] = s; wq[w] = q; }
  __syncthreads();
  s = ws[0] + ws[1] + ws[2] + ws[3];
  q = wq[0] + wq[1] + wq[2] + wq[3];
  float mu = s * (1.0f / DMODEL);
  float var = q * (1.0f / DMODEL) - mu * mu;
  float rs = rsqrtf(var + LN_EPS);
  float4 g = ((const float4*)gamma)[tid];
  float4 b = ((const float4*)beta)[tid];
  float xn0 = (v.x - mu) * rs * g.x + b.x;
  float xn1 = (v.y - mu) * rs * g.y + b.y;
  float xn2 = (v.z - mu) * rs * g.z + b.z;
  float xn3 = (v.w - mu) * rs * g.w + b.w;
  ushort4 hs, ls; unsigned short h;
  h = f2bf(xn0); hs.x = h; ls.x = f2bf(xn0 - bf2f(h));
  h = f2bf(xn1); hs.y = h; ls.y = f2bf(xn1 - bf2f(h));
  h = f2bf(xn2); hs.z = h; ls.z = f2bf(xn2 - bf2f(h));
  h = f2bf(xn3); hs.w = h; ls.w = f2bf(xn3 - bf2f(h));
  unsigned short* dst = xnp + (size_t)row * KPHYS;
  ((ushort4*)dst)[tid] = hs;
  ((ushort4*)(dst + 1024))[tid] = ls;
}

// ---------------- Bm/Cm -> s  (M=16384, N=32, packed K=3072) ----------------
__global__ __launch_bounds__(256) void bc_kernel(
    const unsigned short* __restrict__ XNP, const unsigned short* __restrict__ WbcP,
    const float* __restrict__ bb, const float* __restrict__ bcv, float* __restrict__ S) {
  __shared__ char smem[(64 + 32) * 128];
  char* sA = smem;
  char* sB = smem + 64 * 128;
  const int tid = threadIdx.x;
  const int l = tid & 63;
  const int w = tid >> 6;
  const int m0 = blockIdx.x * 64;
  f32x4 acc0 = {0.f, 0.f, 0.f, 0.f};
  f32x4 acc1 = {0.f, 0.f, 0.f, 0.f};
  for (int kt = 0; kt < KPACK; kt += 64) {
    int ksA = kt < 2048 ? kt : kt - 2048;   // [xh|xl|xh]
    int ksB = kt < 1024 ? kt : kt - 1024;   // [wh|wh|wl]
#pragma unroll
    for (int i = 0; i < 2; ++i) {
      int qq = i * 256 + tid;
      int row = qq >> 3, ch = qq & 7;
      gload16(XNP + (size_t)(m0 + row) * KPHYS + ksA + ((ch ^ (row & 7)) << 3),
              sA + (i * 256 + w * 64) * 16);
    }
    {
      int row = tid >> 3, ch = tid & 7;
      gload16(WbcP + (size_t)row * KPHYS + ksB + ((ch ^ (row & 7)) << 3),
              sB + (w * 64) * 16);
    }
    __syncthreads();
#pragma unroll
    for (int kk = 0; kk < 2; ++kk) {
      int cs = ((kk * 4 + (l >> 4)) ^ (l & 7)) * 16;
      bf16x8 a  = *(const bf16x8*)(sA + (w * 16 + (l & 15)) * 128 + cs);
      bf16x8 b0 = *(const bf16x8*)(sB + ((l & 15)) * 128 + cs);
      bf16x8 b1 = *(const bf16x8*)(sB + (16 + (l & 15)) * 128 + cs);
      acc0 = __builtin_amdgcn_mfma_f32_16x16x32_bf16(a, b0, acc0, 0, 0, 0);
      acc1 = __builtin_amdgcn_mfma_f32_16x16x32_bf16(a, b1, acc1, 0, 0, 0);
    }
    __syncthreads();
  }
  int c = l & 15;
#pragma unroll
  for (int j = 0; j < 4; ++j) {
    float bmv = acc0[j] + bb[c];
    float cmv = acc1[j] + bcv[c];
    float p = bmv * cmv;
    p += __shfl_xor(p, 1, 64);
    p += __shfl_xor(p, 2, 64);
    p += __shfl_xor(p, 4, 64);
    p += __shfl_xor(p, 8, 64);
    if (c == 0) S[m0 + w * 16 + (l >> 4) * 4 + j] = p;
  }
}

// ---------------- 256x256 double-buffered GEMM, low-pressure body ----------
// C[m,n] = sum_k' A[m,k']*B[n,k'] over logical K'=3072 with source remap.
// Per K-tile: two kk-halves, each {12 ds_reads -> 32 MFMA} (max 12 live
// fragments = 48 VGPR; acc 128; total ~200 -> no spill).
// SBAR_F barriers (fenced); MFENCE between prologue STAGEs pins gload issue
// order so counted vmcnt(8) retires exactly the tile about to be read.
// EPI 1: softplus/dt epilogue -> YP (packed h|l).  EPI 2: +bo + residual -> out.
template <int EPI>
__global__ __launch_bounds__(512, 2) void gemm8_kernel(
    const unsigned short* __restrict__ Ag,   // [16384][2048] packed h|l
    const unsigned short* __restrict__ Bg,   // [1024][2048] packed h|l
    const float* __restrict__ e0,            // EPI1: bdt   EPI2: bo
    const float* __restrict__ e1,            // EPI1: Dsk   EPI2: x (residual)
    const float* __restrict__ S,             // EPI1: s
    unsigned short* __restrict__ YP,         // EPI1 out (packed h|l)
    float* __restrict__ outf) {              // EPI2 out
  __shared__ char smem[131072];
  char* const bufA[2] = { smem, smem + 65536 };
  char* const bufB[2] = { smem + 32768, smem + 98304 };

  const int tid = threadIdx.x;
  const int l = tid & 63;
  const int w = tid >> 6;     // 8 waves
  const int wm = w >> 2;      // 0..1  (128 rows each)
  const int wn = w & 3;       // 0..3  (64 cols each)

  // bijective XCD swizzle (grid 256 = 8*32)
  const int bid = blockIdx.x;
  const int sid = (bid & 7) * 32 + (bid >> 3);
  const int m0 = (sid >> 2) * 256;
  const int n0 = (sid & 3) * 256;

  f32x4 acc[8][4];
#pragma unroll
  for (int a = 0; a < 8; ++a)
#pragma unroll
    for (int b = 0; b < 4; ++b) acc[a][b] = (f32x4){0.f, 0.f, 0.f, 0.f};

  // stage one 256x64 K-tile of A and B into buffer bufi (8 gload16/thread)
  auto STAGE = [&](int bufi, int kt) {
    const int ksA = kt < 2048 ? kt : kt - 2048;   // A logical [h|l|h]
    const int ksB = kt < 1024 ? kt : kt - 1024;   // B logical [h|h|l]
#pragma unroll
    for (int r = 0; r < 4; ++r) {
      int qq = r * 512 + tid;
      int row = qq >> 3, ch = qq & 7;
      gload16(Ag + (size_t)(m0 + row) * KPHYS + ksA + ((ch ^ (row & 7)) << 3),
              bufA[bufi] + (r * 512 + w * 64) * 16);
    }
#pragma unroll
    for (int r = 0; r < 4; ++r) {
      int qq = r * 512 + tid;
      int row = qq >> 3, ch = qq & 7;
      gload16(Bg + (size_t)(n0 + row) * KPHYS + ksB + ((ch ^ (row & 7)) << 3),
              bufB[bufi] + (r * 512 + w * 64) * 16);
    }
  };

  const int rbA = (wm * 128 + (l & 15)) * 128;
  const int rbB = (wn * 64 + (l & 15)) * 128;
  int cs[2];
  cs[0] = (((l >> 4)) ^ (l & 7)) * 16;
  cs[1] = ((4 + (l >> 4)) ^ (l & 7)) * 16;

  // half K-step: 12 ds_reads + 32 MFMA, max 12 live frags (48 VGPR)
  auto TILEH = [&](int bufi, int kcs) {
    bf16x8 fA[8], fB[4];
#pragma unroll
    for (int r = 0; r < 8; ++r)
      fA[r] = *(const bf16x8*)(bufA[bufi] + rbA + r * 2048 + kcs);
#pragma unroll
    for (int c = 0; c < 4; ++c)
      fB[c] = *(const bf16x8*)(bufB[bufi] + rbB + c * 2048 + kcs);
    __builtin_amdgcn_s_setprio(1);
#pragma unroll
    for (int r = 0; r < 8; ++r)
#pragma unroll
      for (int c = 0; c < 4; ++c)
        acc[r][c] = __builtin_amdgcn_mfma_f32_16x16x32_bf16(
            fA[r], fB[c], acc[r][c], 0, 0, 0);
    __builtin_amdgcn_s_setprio(0);
  };
  auto TILE = [&](int bufi) {
    TILEH(bufi, cs[0]);
    SCHED0();           // pressure fence between halves (anti-spill)
    TILEH(bufi, cs[1]);
  };

  // prologue: tiles 0,1 in flight. MFENCE between STAGEs: groups must not
  // interleave in issue order, else VMC8's "oldest 8 = tile 0" breaks.
  STAGE(0, 0);
  MFENCE();
  STAGE(1, 64);
  VMC8();
  SBAR_F();

  for (int it = 0; it < 24; ++it) {
    const int kt2 = (it * 128 + 128 <= KPACK - 64) ? it * 128 + 128 : KPACK - 64;
    const int kt3 = (it * 128 + 192 <= KPACK - 64) ? it * 128 + 192 : KPACK - 64;
    // ---- tile 2it (buf0) ----
    TILE(0);
    LGKM0_PIN();        // all buf0 reads retired per-wave
    SBAR_F();           // WAR: no wave's STAGE can start before all reads done
    STAGE(0, kt2);      // overwrite buf0 with tile 2it+2
    VMC8();             // tile 2it+1's loads retired (FIFO: retires all older)
    SBAR_F();           // RAW: buf1 visible workgroup-wide; reads can't hoist
    // ---- tile 2it+1 (buf1) ----
    TILE(1);
    LGKM0_PIN();
    SBAR_F();
    STAGE(1, kt3);
    VMC8();
    SBAR_F();
  }

  // ---------------- epilogue ----------------
  // C/D frag: col = lane&15, row = (lane>>4)*4 + j  (verified)
  // acc[a][b] covers rows wm*128 + a*16, cols wn*64 + b*16
  if constexpr (EPI == 1) {
#pragma unroll
    for (int a = 0; a < 8; ++a) {
      int rw = m0 + wm * 128 + a * 16 + (l >> 4) * 4;
#pragma unroll
      for (int j = 0; j < 4; ++j) {
        int r = rw + j;
        float sv = S[r];
        size_t base = (size_t)r * KPHYS;
#pragma unroll
        for (int b = 0; b < 4; ++b) {
          int col = n0 + wn * 64 + b * 16 + (l & 15);
          float v = acc[a][b][j] + e0[col];
          float sp = fmaxf(v, 0.f) + __logf(1.f + __expf(-fabsf(v)));
          float xnv = bf2f(Ag[base + col]) + bf2f(Ag[base + 1024 + col]);
          float y = sp * xnv * sv + xnv * e1[col];
          unsigned short h = f2bf(y);
          YP[base + col] = h;
          YP[base + 1024 + col] = f2bf(y - bf2f(h));
        }
      }
    }
  } else {
#pragma unroll
    for (int a = 0; a < 8; ++a) {
      int rw = m0 + wm * 128 + a * 16 + (l >> 4) * 4;
#pragma unroll
      for (int j = 0; j < 4; ++j) {
        int r = rw + j;
        size_t base = (size_t)r * DMODEL;
#pragma unroll
        for (int b = 0; b < 4; ++b) {
          int col = n0 + wn * 64 + b * 16 + (l & 15);
          outf[base + col] = acc[a][b][j] + e0[col] + e1[base + col];
        }
      }
    }
  }
}

extern "C" void kernel_launch(void* const* d_in, const int* in_sizes, int n_in,
                              void* d_out, int out_size, void* d_ws, size_t ws_size,
                              hipStream_t stream) {
  const float* x = (const float*)d_in[0];
  const float* gamma = (const float*)d_in[1];
  const float* beta = (const float*)d_in[2];
  const float* Wb = (const float*)d_in[3];
  const float* bb = (const float*)d_in[4];
  const float* Wc = (const float*)d_in[5];
  const float* bc = (const float*)d_in[6];
  const float* Wdt = (const float*)d_in[7];
  const float* bdt = (const float*)d_in[8];
  const float* Dsk = (const float*)d_in[9];
  const float* Wo = (const float*)d_in[10];
  const float* bo = (const float*)d_in[11];
  float* out = (float*)d_out;

  char* ws = (char*)d_ws;
  size_t off = 0;
  auto alloc = [&](size_t bytes) {
    char* p = ws + off;
    off = (off + bytes + 255) & ~(size_t)255;
    return p;
  };
  unsigned short* XNP  = (unsigned short*)alloc((size_t)BATCH * KPHYS * 2);
  unsigned short* YP   = (unsigned short*)alloc((size_t)BATCH * KPHYS * 2);
  unsigned short* WdtP = (unsigned short*)alloc((size_t)DMODEL * KPHYS * 2);
  unsigned short* WoP  = (unsigned short*)alloc((size_t)DMODEL * KPHYS * 2);
  unsigned short* WbcP = (unsigned short*)alloc((size_t)32 * KPHYS * 2);
  float* S = (float*)alloc((size_t)BATCH * 4);

  pack_kernel<<<2080, 256, 0, stream>>>(Wdt, Wo, Wb, Wc, WdtP, WoP, WbcP);
  ln_kernel<<<BATCH, 256, 0, stream>>>(x, gamma, beta, XNP);
  bc_kernel<<<BATCH / 64, 256, 0, stream>>>(XNP, WbcP, bb, bc, S);
  gemm8_kernel<1><<<256, 512, 0, stream>>>(XNP, WdtP, bdt, Dsk, S, YP, nullptr);
  gemm8_kernel<2><<<256, 512, 0, stream>>>(YP, WoP, bo, x, nullptr, nullptr, out);
}

// Round 11
// 316.278 us; speedup vs baseline: 1.2160x; 1.1674x over previous
//
#include <hip/hip_runtime.h>
#include <math.h>

#define BATCH   16384
#define DMODEL  1024
#define KPACK   2048      // logical packed K: [xh|xl] . [wh|wh]  (2-term split)
#define KPHYS   2048      // physical width of packed activation buffers [h|l]
#define BSTR    1024      // physical width of weight h-plane buffers
#define LN_EPS  1e-5f

typedef __bf16 bf16x8 __attribute__((ext_vector_type(8)));
typedef float  f32x4  __attribute__((ext_vector_type(4)));

static __device__ __forceinline__ unsigned short f2bf(float v) {
  union { float f; unsigned u; } c; c.f = v;
  unsigned r = c.u + 0x7fffu + ((c.u >> 16) & 1u);  // RNE
  return (unsigned short)(r >> 16);
}
static __device__ __forceinline__ float bf2f(unsigned short h) {
  union { unsigned u; float f; } c; c.u = ((unsigned)h) << 16;
  return c.f;
}

// async global->LDS, 16B/lane; lds dest = wave-uniform base + lane*16
static __device__ __forceinline__ void gload16(const void* g, void* l) {
  __builtin_amdgcn_global_load_lds(
      (const __attribute__((address_space(1))) void*)g,
      (__attribute__((address_space(3))) void*)l, 16, 0, 0);
}

#define SCHED0() __builtin_amdgcn_sched_barrier(0)
// compiler-only memory fence: pins issue ORDER of gload16 groups (vmcnt is
// FIFO in issue order — counted waits are only exact if groups don't mix)
#define MFENCE() asm volatile("" ::: "memory")
// barrier with compiler memory fences on BOTH sides
#define SBAR_F() do { MFENCE(); __builtin_amdgcn_s_barrier(); MFENCE(); } while (0)
#define VMC8()   do { asm volatile("s_waitcnt vmcnt(8)" ::: "memory"); } while (0)
// all LDS reads retired per-wave; nothing memory-side crosses afterwards
#define LGKM0_PIN() do { asm volatile("s_waitcnt lgkmcnt(0)" ::: "memory"); \
                         __builtin_amdgcn_sched_barrier(0); } while (0)

// ---------------- weight pack: fp32 -> bf16 h-plane only (2-term) ----------
__global__ __launch_bounds__(256) void pack_kernel(
    const float* __restrict__ Wdt, const float* __restrict__ Wo,
    const float* __restrict__ Wb, const float* __restrict__ Wc,
    unsigned short* __restrict__ WdtH, unsigned short* __restrict__ WoH,
    unsigned short* __restrict__ WbcH) {
  int r = blockIdx.x;
  const float* src;
  unsigned short* dst;
  if (r < 1024)      { src = Wdt + (size_t)r * 1024;        dst = WdtH + (size_t)r * BSTR; }
  else if (r < 2048) { src = Wo  + (size_t)(r-1024) * 1024; dst = WoH  + (size_t)(r-1024) * BSTR; }
  else if (r < 2064) { src = Wb  + (size_t)(r-2048) * 1024; dst = WbcH + (size_t)(r-2048) * BSTR; }
  else               { src = Wc  + (size_t)(r-2064) * 1024; dst = WbcH + (size_t)(r-2064+16) * BSTR; }
  int t = threadIdx.x;
  float4 v = ((const float4*)src)[t];
  ushort4 hs;
  hs.x = f2bf(v.x); hs.y = f2bf(v.y); hs.z = f2bf(v.z); hs.w = f2bf(v.w);
  ((ushort4*)dst)[t] = hs;
}

// ---------------- LayerNorm -> packed xn [hi | lo] ----------------
__global__ __launch_bounds__(256) void ln_kernel(
    const float* __restrict__ x, const float* __restrict__ gamma,
    const float* __restrict__ beta, unsigned short* __restrict__ xnp) {
  const int row = blockIdx.x;
  const int tid = threadIdx.x;
  const float4* xr = (const float4*)(x + (size_t)row * DMODEL);
  float4 v = xr[tid];
  float s = v.x + v.y + v.z + v.w;
  float q = v.x * v.x + v.y * v.y + v.z * v.z + v.w * v.w;
#pragma unroll
  for (int m = 1; m < 64; m <<= 1) {
    s += __shfl_xor(s, m, 64);
    q += __shfl_xor(q, m, 64);
  }
  __shared__ float ws[4], wq[4];
  int w = tid >> 6, l = tid & 63;
  if (l == 0) { ws[w] = s; wq[w] = q; }
  __syncthreads();
  s = ws[0] + ws[1] + ws[2] + ws[3];
  q = wq[0] + wq[1] + wq[2] + wq[3];
  float mu = s * (1.0f / DMODEL);
  float var = q * (1.0f / DMODEL) - mu * mu;
  float rs = rsqrtf(var + LN_EPS);
  float4 g = ((const float4*)gamma)[tid];
  float4 b = ((const float4*)beta)[tid];
  float xn0 = (v.x - mu) * rs * g.x + b.x;
  float xn1 = (v.y - mu) * rs * g.y + b.y;
  float xn2 = (v.z - mu) * rs * g.z + b.z;
  float xn3 = (v.w - mu) * rs * g.w + b.w;
  ushort4 hs, ls; unsigned short h;
  h = f2bf(xn0); hs.x = h; ls.x = f2bf(xn0 - bf2f(h));
  h = f2bf(xn1); hs.y = h; ls.y = f2bf(xn1 - bf2f(h));
  h = f2bf(xn2); hs.z = h; ls.z = f2bf(xn2 - bf2f(h));
  h = f2bf(xn3); hs.w = h; ls.w = f2bf(xn3 - bf2f(h));
  unsigned short* dst = xnp + (size_t)row * KPHYS;
  ((ushort4*)dst)[tid] = hs;
  ((ushort4*)(dst + 1024))[tid] = ls;
}

// ---------------- Bm/Cm -> s  (M=16384, N=32, packed K=2048) ----------------
__global__ __launch_bounds__(256) void bc_kernel(
    const unsigned short* __restrict__ XNP, const unsigned short* __restrict__ WbcH,
    const float* __restrict__ bb, const float* __restrict__ bcv, float* __restrict__ S) {
  __shared__ char smem[(64 + 32) * 128];
  char* sA = smem;
  char* sB = smem + 64 * 128;
  const int tid = threadIdx.x;
  const int l = tid & 63;
  const int w = tid >> 6;
  const int m0 = blockIdx.x * 64;
  f32x4 acc0 = {0.f, 0.f, 0.f, 0.f};
  f32x4 acc1 = {0.f, 0.f, 0.f, 0.f};
  for (int kt = 0; kt < KPACK; kt += 64) {
    int ksA = kt;             // [xh|xl] physical
    int ksB = kt & 1023;      // [wh|wh] -> h-plane read twice
#pragma unroll
    for (int i = 0; i < 2; ++i) {
      int qq = i * 256 + tid;
      int row = qq >> 3, ch = qq & 7;
      gload16(XNP + (size_t)(m0 + row) * KPHYS + ksA + ((ch ^ (row & 7)) << 3),
              sA + (i * 256 + w * 64) * 16);
    }
    {
      int row = tid >> 3, ch = tid & 7;
      gload16(WbcH + (size_t)row * BSTR + ksB + ((ch ^ (row & 7)) << 3),
              sB + (w * 64) * 16);
    }
    __syncthreads();
#pragma unroll
    for (int kk = 0; kk < 2; ++kk) {
      int cs = ((kk * 4 + (l >> 4)) ^ (l & 7)) * 16;
      bf16x8 a  = *(const bf16x8*)(sA + (w * 16 + (l & 15)) * 128 + cs);
      bf16x8 b0 = *(const bf16x8*)(sB + ((l & 15)) * 128 + cs);
      bf16x8 b1 = *(const bf16x8*)(sB + (16 + (l & 15)) * 128 + cs);
      acc0 = __builtin_amdgcn_mfma_f32_16x16x32_bf16(a, b0, acc0, 0, 0, 0);
      acc1 = __builtin_amdgcn_mfma_f32_16x16x32_bf16(a, b1, acc1, 0, 0, 0);
    }
    __syncthreads();
  }
  int c = l & 15;
#pragma unroll
  for (int j = 0; j < 4; ++j) {
    float bmv = acc0[j] + bb[c];
    float cmv = acc1[j] + bcv[c];
    float p = bmv * cmv;
    p += __shfl_xor(p, 1, 64);
    p += __shfl_xor(p, 2, 64);
    p += __shfl_xor(p, 4, 64);
    p += __shfl_xor(p, 8, 64);
    if (c == 0) S[m0 + w * 16 + (l >> 4) * 4 + j] = p;
  }
}

// ---------------- 256x256 double-buffered GEMM (2-term packed K=2048) -------
// C[m,n] = sum_k' A[m,k']*B[n,k'];  A: [h|l] identity map, B: h-plane twice.
// Structure byte-identical to the R10 proven-correct schedule.
// EPI 1: softplus/dt epilogue -> YP (packed h|l).  EPI 2: +bo + residual -> out.
template <int EPI>
__global__ __launch_bounds__(512, 2) void gemm8_kernel(
    const unsigned short* __restrict__ Ag,   // [16384][2048] packed h|l
    const unsigned short* __restrict__ Bg,   // [1024][1024] h-plane
    const float* __restrict__ e0,            // EPI1: bdt   EPI2: bo
    const float* __restrict__ e1,            // EPI1: Dsk   EPI2: x (residual)
    const float* __restrict__ S,             // EPI1: s
    unsigned short* __restrict__ YP,         // EPI1 out (packed h|l)
    float* __restrict__ outf) {              // EPI2 out
  __shared__ char smem[131072];
  char* const bufA[2] = { smem, smem + 65536 };
  char* const bufB[2] = { smem + 32768, smem + 98304 };

  const int tid = threadIdx.x;
  const int l = tid & 63;
  const int w = tid >> 6;     // 8 waves
  const int wm = w >> 2;      // 0..1  (128 rows each)
  const int wn = w & 3;       // 0..3  (64 cols each)

  // bijective XCD swizzle (grid 256 = 8*32)
  const int bid = blockIdx.x;
  const int sid = (bid & 7) * 32 + (bid >> 3);
  const int m0 = (sid >> 2) * 256;
  const int n0 = (sid & 3) * 256;

  f32x4 acc[8][4];
#pragma unroll
  for (int a = 0; a < 8; ++a)
#pragma unroll
    for (int b = 0; b < 4; ++b) acc[a][b] = (f32x4){0.f, 0.f, 0.f, 0.f};

  // stage one 256x64 K-tile of A and B into buffer bufi (8 gload16/thread)
  auto STAGE = [&](int bufi, int kt) {
    const int ksA = kt;             // A: [xh|xl] physical == logical
    const int ksB = kt & 1023;      // B: h-plane read twice
#pragma unroll
    for (int r = 0; r < 4; ++r) {
      int qq = r * 512 + tid;
      int row = qq >> 3, ch = qq & 7;
      gload16(Ag + (size_t)(m0 + row) * KPHYS + ksA + ((ch ^ (row & 7)) << 3),
              bufA[bufi] + (r * 512 + w * 64) * 16);
    }
#pragma unroll
    for (int r = 0; r < 4; ++r) {
      int qq = r * 512 + tid;
      int row = qq >> 3, ch = qq & 7;
      gload16(Bg + (size_t)(n0 + row) * BSTR + ksB + ((ch ^ (row & 7)) << 3),
              bufB[bufi] + (r * 512 + w * 64) * 16);
    }
  };

  const int rbA = (wm * 128 + (l & 15)) * 128;
  const int rbB = (wn * 64 + (l & 15)) * 128;
  int cs[2];
  cs[0] = (((l >> 4)) ^ (l & 7)) * 16;
  cs[1] = ((4 + (l >> 4)) ^ (l & 7)) * 16;

  // half K-step: 12 ds_reads + 32 MFMA, max 12 live frags (48 VGPR)
  auto TILEH = [&](int bufi, int kcs) {
    bf16x8 fA[8], fB[4];
#pragma unroll
    for (int r = 0; r < 8; ++r)
      fA[r] = *(const bf16x8*)(bufA[bufi] + rbA + r * 2048 + kcs);
#pragma unroll
    for (int c = 0; c < 4; ++c)
      fB[c] = *(const bf16x8*)(bufB[bufi] + rbB + c * 2048 + kcs);
    __builtin_amdgcn_s_setprio(1);
#pragma unroll
    for (int r = 0; r < 8; ++r)
#pragma unroll
      for (int c = 0; c < 4; ++c)
        acc[r][c] = __builtin_amdgcn_mfma_f32_16x16x32_bf16(
            fA[r], fB[c], acc[r][c], 0, 0, 0);
    __builtin_amdgcn_s_setprio(0);
  };
  auto TILE = [&](int bufi) {
    TILEH(bufi, cs[0]);
    SCHED0();           // pressure fence between halves (anti-spill)
    TILEH(bufi, cs[1]);
  };

  // prologue: tiles 0,1 in flight. MFENCE pins gload issue order.
  STAGE(0, 0);
  MFENCE();
  STAGE(1, 64);
  VMC8();
  SBAR_F();

  for (int it = 0; it < 16; ++it) {   // 32 K-tiles of 64 = K'2048
    const int kt2 = (it * 128 + 128 <= KPACK - 64) ? it * 128 + 128 : KPACK - 64;
    const int kt3 = (it * 128 + 192 <= KPACK - 64) ? it * 128 + 192 : KPACK - 64;
    // ---- tile 2it (buf0) ----
    TILE(0);
    LGKM0_PIN();        // all buf0 reads retired per-wave
    SBAR_F();           // WAR: no wave's STAGE can start before all reads done
    STAGE(0, kt2);      // overwrite buf0 with tile 2it+2
    VMC8();             // tile 2it+1's loads retired (FIFO: retires all older)
    SBAR_F();           // RAW: buf1 visible workgroup-wide; reads can't hoist
    // ---- tile 2it+1 (buf1) ----
    TILE(1);
    LGKM0_PIN();
    SBAR_F();
    STAGE(1, kt3);
    VMC8();
    SBAR_F();
  }

  // ---------------- epilogue ----------------
  // C/D frag: col = lane&15, row = (lane>>4)*4 + j  (verified)
  // acc[a][b] covers rows wm*128 + a*16, cols wn*64 + b*16
  if constexpr (EPI == 1) {
#pragma unroll
    for (int a = 0; a < 8; ++a) {
      int rw = m0 + wm * 128 + a * 16 + (l >> 4) * 4;
#pragma unroll
      for (int j = 0; j < 4; ++j) {
        int r = rw + j;
        float sv = S[r];
        size_t base = (size_t)r * KPHYS;
#pragma unroll
        for (int b = 0; b < 4; ++b) {
          int col = n0 + wn * 64 + b * 16 + (l & 15);
          float v = acc[a][b][j] + e0[col];
          float sp = fmaxf(v, 0.f) + __logf(1.f + __expf(-fabsf(v)));
          float xnv = bf2f(Ag[base + col]) + bf2f(Ag[base + 1024 + col]);
          float y = sp * xnv * sv + xnv * e1[col];
          unsigned short h = f2bf(y);
          YP[base + col] = h;
          YP[base + 1024 + col] = f2bf(y - bf2f(h));
        }
      }
    }
  } else {
#pragma unroll
    for (int a = 0; a < 8; ++a) {
      int rw = m0 + wm * 128 + a * 16 + (l >> 4) * 4;
#pragma unroll
      for (int j = 0; j < 4; ++j) {
        int r = rw + j;
        size_t base = (size_t)r * DMODEL;
#pragma unroll
        for (int b = 0; b < 4; ++b) {
          int col = n0 + wn * 64 + b * 16 + (l & 15);
          outf[base + col] = acc[a][b][j] + e0[col] + e1[base + col];
        }
      }
    }
  }
}

extern "C" void kernel_launch(void* const* d_in, const int* in_sizes, int n_in,
                              void* d_out, int out_size, void* d_ws, size_t ws_size,
                              hipStream_t stream) {
  const float* x = (const float*)d_in[0];
  const float* gamma = (const float*)d_in[1];
  const float* beta = (const float*)d_in[2];
  const float* Wb = (const float*)d_in[3];
  const float* bb = (const float*)d_in[4];
  const float* Wc = (const float*)d_in[5];
  const float* bc = (const float*)d_in[6];
  const float* Wdt = (const float*)d_in[7];
  const float* bdt = (const float*)d_in[8];
  const float* Dsk = (const float*)d_in[9];
  const float* Wo = (const float*)d_in[10];
  const float* bo = (const float*)d_in[11];
  float* out = (float*)d_out;

  char* ws = (char*)d_ws;
  size_t off = 0;
  auto alloc = [&](size_t bytes) {
    char* p = ws + off;
    off = (off + bytes + 255) & ~(size_t)255;
    return p;
  };
  unsigned short* XNP  = (unsigned short*)alloc((size_t)BATCH * KPHYS * 2);
  unsigned short* YP   = (unsigned short*)alloc((size_t)BATCH * KPHYS * 2);
  unsigned short* WdtH = (unsigned short*)alloc((size_t)DMODEL * BSTR * 2);
  unsigned short* WoH  = (unsigned short*)alloc((size_t)DMODEL * BSTR * 2);
  unsigned short* WbcH = (unsigned short*)alloc((size_t)32 * BSTR * 2);
  float* S = (float*)alloc((size_t)BATCH * 4);

  pack_kernel<<<2080, 256, 0, stream>>>(Wdt, Wo, Wb, Wc, WdtH, WoH, WbcH);
  ln_kernel<<<BATCH, 256, 0, stream>>>(x, gamma, beta, XNP);
  bc_kernel<<<BATCH / 64, 256, 0, stream>>>(XNP, WbcH, bb, bc, S);
  gemm8_kernel<1><<<256, 512, 0, stream>>>(XNP, WdtH, bdt, Dsk, S, YP, nullptr);
  gemm8_kernel<2><<<256, 512, 0, stream>>>(YP, WoH, bo, x, nullptr, nullptr, out);
}